// Round 13
// baseline (62.720 us; speedup 1.0000x reference)
//
#include <hip/hip_runtime.h>

#define NN 10000
#define NE 320000
#define RCAP 32    /* per-replica segment capacity */
#define NREP 4
#define BSTRIDE 128

typedef __bf16 bf16x8 __attribute__((ext_vector_type(8)));
typedef float f32x4 __attribute__((ext_vector_type(4)));
typedef unsigned short us8 __attribute__((ext_vector_type(8)));

static __device__ __forceinline__ unsigned short f2bf(float f) {
  union { float fv; unsigned u; } v; v.fv = f;
  unsigned r = v.u + 0x7FFFu + ((v.u >> 16) & 1u);
  return (unsigned short)(r >> 16);
}
static __device__ __forceinline__ float bf2f(unsigned short b) {
  union { unsigned u; float f; } v; v.u = ((unsigned)b) << 16;
  return v.f;
}

// ---- D1: x->bf16 (blocks 0..2499) + cnt zero (4 replicas) + weight
//      transpose (blocks 2500..2531). r8-validated structure. --------------

__global__ __launch_bounds__(256) void conv_k(const float* __restrict__ x,
                                              const float* __restrict__ w1,
                                              const float* __restrict__ w2,
                                              ushort4* __restrict__ xb4,
                                              unsigned short* __restrict__ w1t,
                                              unsigned short* __restrict__ w2t,
                                              int* __restrict__ cnt) {
  __shared__ unsigned short sh[64][72];
  int bid = blockIdx.x, tid = threadIdx.x;
  if (bid < 2500) {
    int t = bid * 256 + tid;
    if (t < 40960) cnt[t] = 0;  // all 4 replica arrays
    float4 v = reinterpret_cast<const float4*>(x)[t];
    ushort4 o;
    o.x = f2bf(v.x); o.y = f2bf(v.y); o.z = f2bf(v.z); o.w = f2bf(v.w);
    xb4[t] = o;
  } else {
    int b2 = bid - 2500;                       // 0..31
    const float* w = (b2 & 16) ? w2 : w1;
    unsigned short* wt = (b2 & 16) ? w2t : w1t;
    int tile = b2 & 15;
    int ki0 = (tile >> 2) * 64, ni0 = (tile & 3) * 64;
    int r = tid >> 4, c = tid & 15;
#pragma unroll
    for (int rr = r; rr < 64; rr += 16) {
      float4 v = *reinterpret_cast<const float4*>(&w[(ki0 + rr) * 256 + ni0 + c * 4]);
      ushort4 o;
      o.x = f2bf(v.x); o.y = f2bf(v.y); o.z = f2bf(v.z); o.w = f2bf(v.w);
      *reinterpret_cast<ushort4*>(&sh[rr][c * 4]) = o;
    }
    __syncthreads();
    int n = tid >> 3, c8 = tid & 7;
#pragma unroll
    for (int nn = n; nn < 64; nn += 32) {
      us8 o;
#pragma unroll
      for (int j = 0; j < 8; ++j) o[j] = sh[c8 * 8 + j][nn];
      *reinterpret_cast<us8*>(&wt[(ni0 + nn) * 256 + ki0 + c8 * 8]) = o;
    }
  }
}

// ---- D2: bucket fill, 4-way replicated counters (edge e+i -> replica i) ---

__global__ __launch_bounds__(256) void fill_k(const int* __restrict__ ei,
                                              int* __restrict__ cnt,
                                              int* __restrict__ bucket) {
  int e = (blockIdx.x * 256 + threadIdx.x) * 4;
  if (e < NE) {
    int4 s = *reinterpret_cast<const int4*>(&ei[e]);
    int4 d = *reinterpret_cast<const int4*>(&ei[NE + e]);
    int p;
    p = atomicAdd(&cnt[d.x], 1);
    if (p < RCAP) bucket[d.x * BSTRIDE + p] = s.x;
    p = atomicAdd(&cnt[10240 + d.y], 1);
    if (p < RCAP) bucket[d.y * BSTRIDE + RCAP + p] = s.y;
    p = atomicAdd(&cnt[20480 + d.z], 1);
    if (p < RCAP) bucket[d.z * BSTRIDE + 2 * RCAP + p] = s.z;
    p = atomicAdd(&cnt[30720 + d.w], 1);
    if (p < RCAP) bucket[d.w * BSTRIDE + 3 * RCAP + p] = s.w;
  }
}

// ---- D3: aggregation v4: ONE node per block, 4 waves = 4 replica segments.
// Each wave runs the r8-validated 8-deep gather pipeline on its ~8-entry
// segment; shfl_xor(32) folds halves; 3-slot LDS folds waves.

__global__ __launch_bounds__(256) void agg_k(const us8* __restrict__ xb8,
                                             const int* __restrict__ cnt,
                                             const int* __restrict__ bucket,
                                             const float* __restrict__ epsp,
                                             unsigned short* __restrict__ hb) {
  __shared__ float part[3][256];
  int tid = threadIdx.x;
  int wave = tid >> 6;                // replica 0..3
  int node = blockIdx.x;              // grid = NN exactly
  int lane = tid & 63;
  int half = lane >> 5, off = lane & 31;
  float e1 = 1.0f + epsp[0];

  float a[8];
  if (wave == 0) {
    us8 sv = xb8[node * 32 + off];
    float selfw = half ? 0.0f : e1;
#pragma unroll
    for (int j = 0; j < 8; ++j) a[j] = bf2f(sv[j]) * selfw;
  } else {
#pragma unroll
    for (int j = 0; j < 8; ++j) a[j] = 0.0f;
  }

  int m = min(cnt[wave * 10240 + node], RCAP);
  const int4* bp4 =
      reinterpret_cast<const int4*>(bucket + node * BSTRIDE + wave * RCAP);
  int4 ia = bp4[0], ib = bp4[1];
  int k = 0;
  while (k + 8 <= m) {
    int4 na = bp4[(k >> 2) + 2];  // prefetch next 8 indices (pad-safe)
    int4 nb = bp4[(k >> 2) + 3];
    int r0 = half ? ia.y : ia.x;
    int r1 = half ? ia.w : ia.z;
    int r2 = half ? ib.y : ib.x;
    int r3 = half ? ib.w : ib.z;
    us8 v0 = xb8[r0 * 32 + off];
    us8 v1 = xb8[r1 * 32 + off];
    us8 v2 = xb8[r2 * 32 + off];
    us8 v3 = xb8[r3 * 32 + off];
#pragma unroll
    for (int j = 0; j < 8; ++j)
      a[j] += (bf2f(v0[j]) + bf2f(v1[j])) + (bf2f(v2[j]) + bf2f(v3[j]));
    ia = na; ib = nb; k += 8;
  }
  int tl = m - k;  // 0..7 remaining, indices live in ia/ib
#pragma unroll
  for (int q = 0; q < 4; ++q) {
    int idx = (q == 0) ? (half ? ia.y : ia.x)
            : (q == 1) ? (half ? ia.w : ia.z)
            : (q == 2) ? (half ? ib.y : ib.x)
                       : (half ? ib.w : ib.z);
    if (2 * q + half < tl) {  // garbage idx never dereferenced
      us8 v = xb8[idx * 32 + off];
#pragma unroll
      for (int j = 0; j < 8; ++j) a[j] += bf2f(v[j]);
    }
  }
#pragma unroll
  for (int j = 0; j < 8; ++j) a[j] += __shfl_xor(a[j], 32);  // fold halves
  if (wave > 0 && half == 0) {
#pragma unroll
    for (int j = 0; j < 8; ++j) part[wave - 1][j * 32 + off] = a[j];
  }
  __syncthreads();
  if (wave == 0 && half == 0) {
    us8 o;
#pragma unroll
    for (int j = 0; j < 8; ++j) {
      float s = a[j] + ((part[0][j * 32 + off] + part[1][j * 32 + off]) +
                        part[2][j * 32 + off]);
      o[j] = f2bf(s);
    }
    *reinterpret_cast<us8*>(&hb[node * 256 + off * 8]) = o;
  }
}

// ---- D4: fused MLP: out = (relu(hb@W1+b1))@W2 + b2 (r3/r8-validated) ------

__global__ __launch_bounds__(256) void mlp_k(const unsigned short* __restrict__ hb,
                                             const unsigned short* __restrict__ w1t,
                                             const float* __restrict__ b1,
                                             const unsigned short* __restrict__ w2t,
                                             const float* __restrict__ b2,
                                             float* __restrict__ out) {
  __shared__ unsigned short As[32][264];
  __shared__ unsigned short Bs[256][72];
  int m0 = blockIdx.x * 32;
  int tid = threadIdx.x;
  int lane = tid & 63, wave = tid >> 6;
  int waveM = wave & 1, waveN = wave >> 1;
  int l15 = lane & 15, g = lane >> 4;
#pragma unroll
  for (int i = 0; i < 4; ++i) {
    int c = tid + i * 256;
    int r = c >> 5, cc = c & 31;
    int4 v = (m0 + r < NN)
                 ? *reinterpret_cast<const int4*>(&hb[(m0 + r) * 256 + cc * 8])
                 : make_int4(0, 0, 0, 0);
    *reinterpret_cast<int4*>(&As[r][cc * 8]) = v;
  }
  float bias1[8], bias2[8];
#pragma unroll
  for (int ni = 0; ni < 8; ++ni) {
    int col = waveN * 128 + ni * 16 + l15;
    bias1[ni] = b1[col];
    bias2[ni] = b2[col];
  }
  f32x4 acc[8];
#pragma unroll
  for (int ni = 0; ni < 8; ++ni) acc[ni] = f32x4{0.f, 0.f, 0.f, 0.f};
  for (int k0 = 0; k0 < 256; k0 += 64) {
#pragma unroll
    for (int i = 0; i < 8; ++i) {
      int c = tid + i * 256;
      int n = c >> 3, kc = c & 7;
      *reinterpret_cast<int4*>(&Bs[n][kc * 8]) =
          *reinterpret_cast<const int4*>(&w1t[n * 256 + k0 + kc * 8]);
    }
    __syncthreads();
#pragma unroll
    for (int kk = 0; kk < 2; ++kk) {
      bf16x8 af = *reinterpret_cast<const bf16x8*>(
          &As[waveM * 16 + l15][k0 + kk * 32 + g * 8]);
#pragma unroll
      for (int ni = 0; ni < 8; ++ni) {
        bf16x8 bfr = *reinterpret_cast<const bf16x8*>(
            &Bs[waveN * 128 + ni * 16 + l15][kk * 32 + g * 8]);
        acc[ni] = __builtin_amdgcn_mfma_f32_16x16x32_bf16(af, bfr, acc[ni], 0, 0, 0);
      }
    }
    __syncthreads();
  }
#pragma unroll
  for (int ni = 0; ni < 8; ++ni) {
    int col = waveN * 128 + ni * 16 + l15;
#pragma unroll
    for (int r = 0; r < 4; ++r) {
      int row = waveM * 16 + g * 4 + r;
      As[row][col] = f2bf(fmaxf(acc[ni][r] + bias1[ni], 0.f));
    }
    acc[ni] = f32x4{0.f, 0.f, 0.f, 0.f};
  }
  for (int k0 = 0; k0 < 256; k0 += 64) {
#pragma unroll
    for (int i = 0; i < 8; ++i) {
      int c = tid + i * 256;
      int n = c >> 3, kc = c & 7;
      *reinterpret_cast<int4*>(&Bs[n][kc * 8]) =
          *reinterpret_cast<const int4*>(&w2t[n * 256 + k0 + kc * 8]);
    }
    __syncthreads();
#pragma unroll
    for (int kk = 0; kk < 2; ++kk) {
      bf16x8 af = *reinterpret_cast<const bf16x8*>(
          &As[waveM * 16 + l15][k0 + kk * 32 + g * 8]);
#pragma unroll
      for (int ni = 0; ni < 8; ++ni) {
        bf16x8 bfr = *reinterpret_cast<const bf16x8*>(
            &Bs[waveN * 128 + ni * 16 + l15][kk * 32 + g * 8]);
        acc[ni] = __builtin_amdgcn_mfma_f32_16x16x32_bf16(af, bfr, acc[ni], 0, 0, 0);
      }
    }
    __syncthreads();
  }
#pragma unroll
  for (int ni = 0; ni < 8; ++ni) {
    int col = waveN * 128 + ni * 16 + l15;
#pragma unroll
    for (int r = 0; r < 4; ++r) {
      int row = m0 + waveM * 16 + g * 4 + r;
      if (row < NN) out[row * 256 + col] = acc[ni][r] + bias2[ni];
    }
  }
}

// ---- launch ---------------------------------------------------------------

extern "C" void kernel_launch(void* const* d_in, const int* in_sizes, int n_in,
                              void* d_out, int out_size, void* d_ws, size_t ws_size,
                              hipStream_t stream) {
  const float* x = (const float*)d_in[0];
  const int* ei = (const int*)d_in[1];
  const float* w1 = (const float*)d_in[2];
  const float* b1 = (const float*)d_in[3];
  const float* w2 = (const float*)d_in[4];
  const float* b2 = (const float*)d_in[5];
  const float* eps = (const float*)d_in[6];
  float* out = (float*)d_out;

  // workspace layout (16B aligned throughout)
  int* cnt = (int*)d_ws;                              // 4 x 10240 ints
  int* bucket = cnt + 40960;                          // NN*BSTRIDE + 64 pad ints
  unsigned short* xb = (unsigned short*)(bucket + NN * BSTRIDE + 64);
  unsigned short* w1t = xb + NN * 256;                // 65536 bf16
  unsigned short* w2t = w1t + 65536;                  // 65536 bf16
  unsigned short* hb = w2t + 65536;                   // NN*256 bf16

  conv_k<<<2532, 256, 0, stream>>>(x, w1, w2, (ushort4*)xb, w1t, w2t, cnt);
  fill_k<<<(NE / 4 + 255) / 256, 256, 0, stream>>>(ei, cnt, bucket);
  agg_k<<<NN, 256, 0, stream>>>((const us8*)xb, cnt, bucket, eps, hb);
  mlp_k<<<(NN + 31) / 32, 256, 0, stream>>>(hb, w1t, b1, w2t, b2, out);
}

// Round 14
// 59.726 us; speedup vs baseline: 1.0501x; 1.0501x over previous
//
#include <hip/hip_runtime.h>

#define NN 10000
#define NE 320000
#define RCAP 64   /* per-replica segment capacity */
#define BSTRIDE 128

typedef __bf16 bf16x8 __attribute__((ext_vector_type(8)));
typedef float f32x4 __attribute__((ext_vector_type(4)));
typedef unsigned short us8 __attribute__((ext_vector_type(8)));

static __device__ __forceinline__ unsigned short f2bf(float f) {
  union { float fv; unsigned u; } v; v.fv = f;
  unsigned r = v.u + 0x7FFFu + ((v.u >> 16) & 1u);
  return (unsigned short)(r >> 16);
}
static __device__ __forceinline__ float bf2f(unsigned short b) {
  union { unsigned u; float f; } v; v.u = ((unsigned)b) << 16;
  return v.f;
}

// ---- D1: x->bf16 (blocks 0..2499) + cnt zero (both replicas) + weight
//      transpose (blocks 2500..2531). r12-validated verbatim. --------------

__global__ __launch_bounds__(256) void conv_k(const float* __restrict__ x,
                                              const float* __restrict__ w1,
                                              const float* __restrict__ w2,
                                              ushort4* __restrict__ xb4,
                                              unsigned short* __restrict__ w1t,
                                              unsigned short* __restrict__ w2t,
                                              int* __restrict__ cnt) {
  __shared__ unsigned short sh[64][72];
  int bid = blockIdx.x, tid = threadIdx.x;
  if (bid < 2500) {
    int t = bid * 256 + tid;
    if (t < 20480) cnt[t] = 0;  // both replica arrays
    float4 v = reinterpret_cast<const float4*>(x)[t];
    ushort4 o;
    o.x = f2bf(v.x); o.y = f2bf(v.y); o.z = f2bf(v.z); o.w = f2bf(v.w);
    xb4[t] = o;
  } else {
    int b2 = bid - 2500;                       // 0..31
    const float* w = (b2 & 16) ? w2 : w1;
    unsigned short* wt = (b2 & 16) ? w2t : w1t;
    int tile = b2 & 15;
    int ki0 = (tile >> 2) * 64, ni0 = (tile & 3) * 64;
    int r = tid >> 4, c = tid & 15;
#pragma unroll
    for (int rr = r; rr < 64; rr += 16) {
      float4 v = *reinterpret_cast<const float4*>(&w[(ki0 + rr) * 256 + ni0 + c * 4]);
      ushort4 o;
      o.x = f2bf(v.x); o.y = f2bf(v.y); o.z = f2bf(v.z); o.w = f2bf(v.w);
      *reinterpret_cast<ushort4*>(&sh[rr][c * 4]) = o;
    }
    __syncthreads();
    int n = tid >> 3, c8 = tid & 7;
#pragma unroll
    for (int nn = n; nn < 64; nn += 32) {
      us8 o;
#pragma unroll
      for (int j = 0; j < 8; ++j) o[j] = sh[c8 * 8 + j][nn];
      *reinterpret_cast<us8*>(&wt[(ni0 + nn) * 256 + ki0 + c8 * 8]) = o;
    }
  }
}

// ---- D2: bucket fill, 2-way replicated counters (r12-validated verbatim) --

__global__ __launch_bounds__(256) void fill_k(const int* __restrict__ ei,
                                              int* __restrict__ cnt,
                                              int* __restrict__ bucket) {
  int e = (blockIdx.x * 256 + threadIdx.x) * 4;
  if (e < NE) {
    int4 s = *reinterpret_cast<const int4*>(&ei[e]);
    int4 d = *reinterpret_cast<const int4*>(&ei[NE + e]);
    int p;
    p = atomicAdd(&cnt[d.x], 1);
    if (p < RCAP) bucket[d.x * BSTRIDE + p] = s.x;
    p = atomicAdd(&cnt[10240 + d.y], 1);
    if (p < RCAP) bucket[d.y * BSTRIDE + RCAP + p] = s.y;
    p = atomicAdd(&cnt[d.z], 1);
    if (p < RCAP) bucket[d.z * BSTRIDE + p] = s.z;
    p = atomicAdd(&cnt[10240 + d.w], 1);
    if (p < RCAP) bucket[d.w * BSTRIDE + RCAP + p] = s.w;
  }
}

// ---- D3: aggregation v2r (r12-validated verbatim): 2 waves/node, wave p
//      owns replica-p segment; 8-deep us8 gather pipeline. -----------------

__global__ __launch_bounds__(256) void agg_k(const us8* __restrict__ xb8,
                                             const int* __restrict__ cnt,
                                             const int* __restrict__ bucket,
                                             const float* __restrict__ epsp,
                                             unsigned short* __restrict__ hb) {
  __shared__ float part[2][256];
  int tid = threadIdx.x;
  int wave = tid >> 6;
  int slot = wave >> 1;   // which node of the block's pair
  int p = wave & 1;       // which replica segment
  int node = blockIdx.x * 2 + slot;   // grid = NN/2 exactly
  int lane = tid & 63;
  int half = lane >> 5, off = lane & 31;
  float e1 = 1.0f + epsp[0];

  float a[8];
  if (p == 0) {
    us8 sv = xb8[node * 32 + off];
    float selfw = half ? 0.0f : e1;
#pragma unroll
    for (int j = 0; j < 8; ++j) a[j] = bf2f(sv[j]) * selfw;
  } else {
#pragma unroll
    for (int j = 0; j < 8; ++j) a[j] = 0.0f;
  }

  int m = min(cnt[p * 10240 + node], RCAP);
  const int4* bp4 = reinterpret_cast<const int4*>(bucket + node * BSTRIDE + p * RCAP);
  int4 ia = bp4[0], ib = bp4[1];
  int k = 0;
  while (k + 8 <= m) {
    int4 na = bp4[(k >> 2) + 2];  // prefetch next 8 indices (pad-safe)
    int4 nb = bp4[(k >> 2) + 3];
    int r0 = half ? ia.y : ia.x;
    int r1 = half ? ia.w : ia.z;
    int r2 = half ? ib.y : ib.x;
    int r3 = half ? ib.w : ib.z;
    us8 v0 = xb8[r0 * 32 + off];
    us8 v1 = xb8[r1 * 32 + off];
    us8 v2 = xb8[r2 * 32 + off];
    us8 v3 = xb8[r3 * 32 + off];
#pragma unroll
    for (int j = 0; j < 8; ++j)
      a[j] += (bf2f(v0[j]) + bf2f(v1[j])) + (bf2f(v2[j]) + bf2f(v3[j]));
    ia = na; ib = nb; k += 8;
  }
  int tl = m - k;  // 0..7 remaining, indices live in ia/ib
#pragma unroll
  for (int q = 0; q < 4; ++q) {
    int idx = (q == 0) ? (half ? ia.y : ia.x)
            : (q == 1) ? (half ? ia.w : ia.z)
            : (q == 2) ? (half ? ib.y : ib.x)
                       : (half ? ib.w : ib.z);
    if (2 * q + half < tl) {  // garbage idx never dereferenced
      us8 v = xb8[idx * 32 + off];
#pragma unroll
      for (int j = 0; j < 8; ++j) a[j] += bf2f(v[j]);
    }
  }
#pragma unroll
  for (int j = 0; j < 8; ++j) a[j] += __shfl_xor(a[j], 32);  // combine halves
  if (p == 1 && half == 0) {
#pragma unroll
    for (int j = 0; j < 8; ++j) part[slot][j * 32 + off] = a[j];
  }
  __syncthreads();
  if (p == 0 && half == 0) {
    us8 o;
#pragma unroll
    for (int j = 0; j < 8; ++j) o[j] = f2bf(a[j] + part[slot][j * 32 + off]);
    *reinterpret_cast<us8*>(&hb[node * 256 + off * 8]) = o;
  }
}

// ---- D4: fused MLP, 64-row tiles, 512 threads, 8 waves (2M x 4N). ---------
// Same fragment math / k-chunk order as the validated 32-row kernel (output
// bitwise identical); halves weight re-streaming (157 vs 313 blocks) and
// doubles per-block waves for barrier overlap.

__global__ __launch_bounds__(512) void mlp_k(const unsigned short* __restrict__ hb,
                                             const unsigned short* __restrict__ w1t,
                                             const float* __restrict__ b1,
                                             const unsigned short* __restrict__ w2t,
                                             const float* __restrict__ b2,
                                             float* __restrict__ out) {
  __shared__ unsigned short As[64][264];  // 33.8 KB
  __shared__ unsigned short Bs[256][72];  // 36.9 KB
  int m0 = blockIdx.x * 64;
  int tid = threadIdx.x;
  int lane = tid & 63, wave = tid >> 6;   // 8 waves
  int waveM = wave & 1, waveN = wave >> 1;  // 2M x 4N
  int l15 = lane & 15, g = lane >> 4;

  // A tile: 64 rows x 256 cols = 2048 int4, 4/thread
#pragma unroll
  for (int i = 0; i < 4; ++i) {
    int c = tid + i * 512;
    int r = c >> 5, cc = c & 31;
    int4 v = (m0 + r < NN)
                 ? *reinterpret_cast<const int4*>(&hb[(m0 + r) * 256 + cc * 8])
                 : make_int4(0, 0, 0, 0);
    *reinterpret_cast<int4*>(&As[r][cc * 8]) = v;
  }
  float bias1[4], bias2[4];
#pragma unroll
  for (int ni = 0; ni < 4; ++ni) {
    int col = waveN * 64 + ni * 16 + l15;
    bias1[ni] = b1[col];
    bias2[ni] = b2[col];
  }
  f32x4 acc[2][4];
#pragma unroll
  for (int mi = 0; mi < 2; ++mi)
#pragma unroll
    for (int ni = 0; ni < 4; ++ni) acc[mi][ni] = f32x4{0.f, 0.f, 0.f, 0.f};

  // GEMM1
  for (int k0 = 0; k0 < 256; k0 += 64) {
#pragma unroll
    for (int i = 0; i < 4; ++i) {  // stage Bs: 2048 int4, 4/thread
      int c = tid + i * 512;
      int n = c >> 3, kc = c & 7;
      *reinterpret_cast<int4*>(&Bs[n][kc * 8]) =
          *reinterpret_cast<const int4*>(&w1t[n * 256 + k0 + kc * 8]);
    }
    __syncthreads();
#pragma unroll
    for (int kk = 0; kk < 2; ++kk) {
#pragma unroll
      for (int mi = 0; mi < 2; ++mi) {
        bf16x8 af = *reinterpret_cast<const bf16x8*>(
            &As[waveM * 32 + mi * 16 + l15][k0 + kk * 32 + g * 8]);
#pragma unroll
        for (int ni = 0; ni < 4; ++ni) {
          bf16x8 bfr = *reinterpret_cast<const bf16x8*>(
              &Bs[waveN * 64 + ni * 16 + l15][kk * 32 + g * 8]);
          acc[mi][ni] =
              __builtin_amdgcn_mfma_f32_16x16x32_bf16(af, bfr, acc[mi][ni], 0, 0, 0);
        }
      }
    }
    __syncthreads();
  }
  // relu back into As
#pragma unroll
  for (int mi = 0; mi < 2; ++mi) {
#pragma unroll
    for (int ni = 0; ni < 4; ++ni) {
      int col = waveN * 64 + ni * 16 + l15;
#pragma unroll
      for (int r = 0; r < 4; ++r) {
        int row = waveM * 32 + mi * 16 + g * 4 + r;
        As[row][col] = f2bf(fmaxf(acc[mi][ni][r] + bias1[ni], 0.f));
      }
      acc[mi][ni] = f32x4{0.f, 0.f, 0.f, 0.f};
    }
  }
  // GEMM2
  for (int k0 = 0; k0 < 256; k0 += 64) {
#pragma unroll
    for (int i = 0; i < 4; ++i) {
      int c = tid + i * 512;
      int n = c >> 3, kc = c & 7;
      *reinterpret_cast<int4*>(&Bs[n][kc * 8]) =
          *reinterpret_cast<const int4*>(&w2t[n * 256 + k0 + kc * 8]);
    }
    __syncthreads();
#pragma unroll
    for (int kk = 0; kk < 2; ++kk) {
#pragma unroll
      for (int mi = 0; mi < 2; ++mi) {
        bf16x8 af = *reinterpret_cast<const bf16x8*>(
            &As[waveM * 32 + mi * 16 + l15][k0 + kk * 32 + g * 8]);
#pragma unroll
        for (int ni = 0; ni < 4; ++ni) {
          bf16x8 bfr = *reinterpret_cast<const bf16x8*>(
              &Bs[waveN * 64 + ni * 16 + l15][kk * 32 + g * 8]);
          acc[mi][ni] =
              __builtin_amdgcn_mfma_f32_16x16x32_bf16(af, bfr, acc[mi][ni], 0, 0, 0);
        }
      }
    }
    __syncthreads();
  }
  // epilogue
#pragma unroll
  for (int mi = 0; mi < 2; ++mi) {
#pragma unroll
    for (int ni = 0; ni < 4; ++ni) {
      int col = waveN * 64 + ni * 16 + l15;
#pragma unroll
      for (int r = 0; r < 4; ++r) {
        int row = m0 + waveM * 32 + mi * 16 + g * 4 + r;
        if (row < NN) out[row * 256 + col] = acc[mi][ni][r] + bias2[ni];
      }
    }
  }
}

// ---- launch ---------------------------------------------------------------

extern "C" void kernel_launch(void* const* d_in, const int* in_sizes, int n_in,
                              void* d_out, int out_size, void* d_ws, size_t ws_size,
                              hipStream_t stream) {
  const float* x = (const float*)d_in[0];
  const int* ei = (const int*)d_in[1];
  const float* w1 = (const float*)d_in[2];
  const float* b1 = (const float*)d_in[3];
  const float* w2 = (const float*)d_in[4];
  const float* b2 = (const float*)d_in[5];
  const float* eps = (const float*)d_in[6];
  float* out = (float*)d_out;

  // workspace layout (16B aligned throughout)
  int* cnt = (int*)d_ws;                              // 2 x 10240 ints
  int* bucket = cnt + 20480;                          // NN*BSTRIDE + 32 pad ints
  unsigned short* xb = (unsigned short*)(bucket + NN * BSTRIDE + 32);
  unsigned short* w1t = xb + NN * 256;                // 65536 bf16
  unsigned short* w2t = w1t + 65536;                  // 65536 bf16
  unsigned short* hb = w2t + 65536;                   // NN*256 bf16

  conv_k<<<2532, 256, 0, stream>>>(x, w1, w2, (ushort4*)xb, w1t, w2t, cnt);
  fill_k<<<(NE / 4 + 255) / 256, 256, 0, stream>>>(ei, cnt, bucket);
  agg_k<<<NN / 2, 256, 0, stream>>>((const us8*)xb, cnt, bucket, eps, hb);
  mlp_k<<<(NN + 63) / 64, 512, 0, stream>>>(hb, w1t, b1, w2t, b2, out);
}

// Round 15
// 59.321 us; speedup vs baseline: 1.0573x; 1.0068x over previous
//
#include <hip/hip_runtime.h>

#define NN 10000
#define NE 320000
#define RCAP 64   /* per-replica segment capacity */
#define BSTRIDE 128

typedef __bf16 bf16x8 __attribute__((ext_vector_type(8)));
typedef float f32x4 __attribute__((ext_vector_type(4)));
typedef unsigned short us8 __attribute__((ext_vector_type(8)));

static __device__ __forceinline__ unsigned short f2bf(float f) {
  union { float fv; unsigned u; } v; v.fv = f;
  unsigned r = v.u + 0x7FFFu + ((v.u >> 16) & 1u);
  return (unsigned short)(r >> 16);
}
static __device__ __forceinline__ float bf2f(unsigned short b) {
  union { unsigned u; float f; } v; v.u = ((unsigned)b) << 16;
  return v.f;
}

// ---- D1: x->bf16 (blocks 0..624, 4 float4/thread) + cnt zero (first 80
//      blocks) + weight transpose (blocks 625..656). ------------------------

__global__ __launch_bounds__(256) void conv_k(const float* __restrict__ x,
                                              const float* __restrict__ w1,
                                              const float* __restrict__ w2,
                                              ushort4* __restrict__ xb4,
                                              unsigned short* __restrict__ w1t,
                                              unsigned short* __restrict__ w2t,
                                              int* __restrict__ cnt) {
  __shared__ unsigned short sh[64][72];
  int bid = blockIdx.x, tid = threadIdx.x;
  if (bid < 625) {
    int t0 = bid * 256 + tid;
    if (t0 < 20480) cnt[t0] = 0;  // both replica arrays
    int base = bid * 1024 + tid;
    float4 v0 = reinterpret_cast<const float4*>(x)[base];
    float4 v1 = reinterpret_cast<const float4*>(x)[base + 256];
    float4 v2 = reinterpret_cast<const float4*>(x)[base + 512];
    float4 v3 = reinterpret_cast<const float4*>(x)[base + 768];
    ushort4 o0, o1, o2, o3;
    o0.x = f2bf(v0.x); o0.y = f2bf(v0.y); o0.z = f2bf(v0.z); o0.w = f2bf(v0.w);
    o1.x = f2bf(v1.x); o1.y = f2bf(v1.y); o1.z = f2bf(v1.z); o1.w = f2bf(v1.w);
    o2.x = f2bf(v2.x); o2.y = f2bf(v2.y); o2.z = f2bf(v2.z); o2.w = f2bf(v2.w);
    o3.x = f2bf(v3.x); o3.y = f2bf(v3.y); o3.z = f2bf(v3.z); o3.w = f2bf(v3.w);
    xb4[base] = o0;
    xb4[base + 256] = o1;
    xb4[base + 512] = o2;
    xb4[base + 768] = o3;
  } else {
    int b2 = bid - 625;                        // 0..31
    const float* w = (b2 & 16) ? w2 : w1;
    unsigned short* wt = (b2 & 16) ? w2t : w1t;
    int tile = b2 & 15;
    int ki0 = (tile >> 2) * 64, ni0 = (tile & 3) * 64;
    int r = tid >> 4, c = tid & 15;
#pragma unroll
    for (int rr = r; rr < 64; rr += 16) {
      float4 v = *reinterpret_cast<const float4*>(&w[(ki0 + rr) * 256 + ni0 + c * 4]);
      ushort4 o;
      o.x = f2bf(v.x); o.y = f2bf(v.y); o.z = f2bf(v.z); o.w = f2bf(v.w);
      *reinterpret_cast<ushort4*>(&sh[rr][c * 4]) = o;
    }
    __syncthreads();
    int n = tid >> 3, c8 = tid & 7;
#pragma unroll
    for (int nn = n; nn < 64; nn += 32) {
      us8 o;
#pragma unroll
      for (int j = 0; j < 8; ++j) o[j] = sh[c8 * 8 + j][nn];
      *reinterpret_cast<us8*>(&wt[(ni0 + nn) * 256 + ki0 + c8 * 8]) = o;
    }
  }
}

// ---- D2: bucket fill, 2-way replicated counters (r12-validated verbatim) --

__global__ __launch_bounds__(256) void fill_k(const int* __restrict__ ei,
                                              int* __restrict__ cnt,
                                              int* __restrict__ bucket) {
  int e = (blockIdx.x * 256 + threadIdx.x) * 4;
  if (e < NE) {
    int4 s = *reinterpret_cast<const int4*>(&ei[e]);
    int4 d = *reinterpret_cast<const int4*>(&ei[NE + e]);
    int p;
    p = atomicAdd(&cnt[d.x], 1);
    if (p < RCAP) bucket[d.x * BSTRIDE + p] = s.x;
    p = atomicAdd(&cnt[10240 + d.y], 1);
    if (p < RCAP) bucket[d.y * BSTRIDE + RCAP + p] = s.y;
    p = atomicAdd(&cnt[d.z], 1);
    if (p < RCAP) bucket[d.z * BSTRIDE + p] = s.z;
    p = atomicAdd(&cnt[10240 + d.w], 1);
    if (p < RCAP) bucket[d.w * BSTRIDE + RCAP + p] = s.w;
  }
}

// ---- D3: aggregation v2r (r12-validated verbatim): 2 waves/node, wave p
//      owns replica-p segment; 8-deep us8 gather pipeline. -----------------

__global__ __launch_bounds__(256) void agg_k(const us8* __restrict__ xb8,
                                             const int* __restrict__ cnt,
                                             const int* __restrict__ bucket,
                                             const float* __restrict__ epsp,
                                             unsigned short* __restrict__ hb) {
  __shared__ float part[2][256];
  int tid = threadIdx.x;
  int wave = tid >> 6;
  int slot = wave >> 1;   // which node of the block's pair
  int p = wave & 1;       // which replica segment
  int node = blockIdx.x * 2 + slot;   // grid = NN/2 exactly
  int lane = tid & 63;
  int half = lane >> 5, off = lane & 31;
  float e1 = 1.0f + epsp[0];

  float a[8];
  if (p == 0) {
    us8 sv = xb8[node * 32 + off];
    float selfw = half ? 0.0f : e1;
#pragma unroll
    for (int j = 0; j < 8; ++j) a[j] = bf2f(sv[j]) * selfw;
  } else {
#pragma unroll
    for (int j = 0; j < 8; ++j) a[j] = 0.0f;
  }

  int m = min(cnt[p * 10240 + node], RCAP);
  const int4* bp4 = reinterpret_cast<const int4*>(bucket + node * BSTRIDE + p * RCAP);
  int4 ia = bp4[0], ib = bp4[1];
  int k = 0;
  while (k + 8 <= m) {
    int4 na = bp4[(k >> 2) + 2];  // prefetch next 8 indices (pad-safe)
    int4 nb = bp4[(k >> 2) + 3];
    int r0 = half ? ia.y : ia.x;
    int r1 = half ? ia.w : ia.z;
    int r2 = half ? ib.y : ib.x;
    int r3 = half ? ib.w : ib.z;
    us8 v0 = xb8[r0 * 32 + off];
    us8 v1 = xb8[r1 * 32 + off];
    us8 v2 = xb8[r2 * 32 + off];
    us8 v3 = xb8[r3 * 32 + off];
#pragma unroll
    for (int j = 0; j < 8; ++j)
      a[j] += (bf2f(v0[j]) + bf2f(v1[j])) + (bf2f(v2[j]) + bf2f(v3[j]));
    ia = na; ib = nb; k += 8;
  }
  int tl = m - k;  // 0..7 remaining, indices live in ia/ib
#pragma unroll
  for (int q = 0; q < 4; ++q) {
    int idx = (q == 0) ? (half ? ia.y : ia.x)
            : (q == 1) ? (half ? ia.w : ia.z)
            : (q == 2) ? (half ? ib.y : ib.x)
                       : (half ? ib.w : ib.z);
    if (2 * q + half < tl) {  // garbage idx never dereferenced
      us8 v = xb8[idx * 32 + off];
#pragma unroll
      for (int j = 0; j < 8; ++j) a[j] += bf2f(v[j]);
    }
  }
#pragma unroll
  for (int j = 0; j < 8; ++j) a[j] += __shfl_xor(a[j], 32);  // combine halves
  if (p == 1 && half == 0) {
#pragma unroll
    for (int j = 0; j < 8; ++j) part[slot][j * 32 + off] = a[j];
  }
  __syncthreads();
  if (p == 0 && half == 0) {
    us8 o;
#pragma unroll
    for (int j = 0; j < 8; ++j) o[j] = f2bf(a[j] + part[slot][j * 32 + off]);
    *reinterpret_cast<us8*>(&hb[node * 256 + off * 8]) = o;
  }
}

// ---- D4: fused MLP, 64-row tiles, 512 threads (r14-validated verbatim) ----

__global__ __launch_bounds__(512) void mlp_k(const unsigned short* __restrict__ hb,
                                             const unsigned short* __restrict__ w1t,
                                             const float* __restrict__ b1,
                                             const unsigned short* __restrict__ w2t,
                                             const float* __restrict__ b2,
                                             float* __restrict__ out) {
  __shared__ unsigned short As[64][264];  // 33.8 KB
  __shared__ unsigned short Bs[256][72];  // 36.9 KB
  int m0 = blockIdx.x * 64;
  int tid = threadIdx.x;
  int lane = tid & 63, wave = tid >> 6;   // 8 waves
  int waveM = wave & 1, waveN = wave >> 1;  // 2M x 4N
  int l15 = lane & 15, g = lane >> 4;

#pragma unroll
  for (int i = 0; i < 4; ++i) {
    int c = tid + i * 512;
    int r = c >> 5, cc = c & 31;
    int4 v = (m0 + r < NN)
                 ? *reinterpret_cast<const int4*>(&hb[(m0 + r) * 256 + cc * 8])
                 : make_int4(0, 0, 0, 0);
    *reinterpret_cast<int4*>(&As[r][cc * 8]) = v;
  }
  float bias1[4], bias2[4];
#pragma unroll
  for (int ni = 0; ni < 4; ++ni) {
    int col = waveN * 64 + ni * 16 + l15;
    bias1[ni] = b1[col];
    bias2[ni] = b2[col];
  }
  f32x4 acc[2][4];
#pragma unroll
  for (int mi = 0; mi < 2; ++mi)
#pragma unroll
    for (int ni = 0; ni < 4; ++ni) acc[mi][ni] = f32x4{0.f, 0.f, 0.f, 0.f};

  // GEMM1
  for (int k0 = 0; k0 < 256; k0 += 64) {
#pragma unroll
    for (int i = 0; i < 4; ++i) {
      int c = tid + i * 512;
      int n = c >> 3, kc = c & 7;
      *reinterpret_cast<int4*>(&Bs[n][kc * 8]) =
          *reinterpret_cast<const int4*>(&w1t[n * 256 + k0 + kc * 8]);
    }
    __syncthreads();
#pragma unroll
    for (int kk = 0; kk < 2; ++kk) {
#pragma unroll
      for (int mi = 0; mi < 2; ++mi) {
        bf16x8 af = *reinterpret_cast<const bf16x8*>(
            &As[waveM * 32 + mi * 16 + l15][k0 + kk * 32 + g * 8]);
#pragma unroll
        for (int ni = 0; ni < 4; ++ni) {
          bf16x8 bfr = *reinterpret_cast<const bf16x8*>(
              &Bs[waveN * 64 + ni * 16 + l15][kk * 32 + g * 8]);
          acc[mi][ni] =
              __builtin_amdgcn_mfma_f32_16x16x32_bf16(af, bfr, acc[mi][ni], 0, 0, 0);
        }
      }
    }
    __syncthreads();
  }
  // relu back into As
#pragma unroll
  for (int mi = 0; mi < 2; ++mi) {
#pragma unroll
    for (int ni = 0; ni < 4; ++ni) {
      int col = waveN * 64 + ni * 16 + l15;
#pragma unroll
      for (int r = 0; r < 4; ++r) {
        int row = waveM * 32 + mi * 16 + g * 4 + r;
        As[row][col] = f2bf(fmaxf(acc[mi][ni][r] + bias1[ni], 0.f));
      }
      acc[mi][ni] = f32x4{0.f, 0.f, 0.f, 0.f};
    }
  }
  // GEMM2
  for (int k0 = 0; k0 < 256; k0 += 64) {
#pragma unroll
    for (int i = 0; i < 4; ++i) {
      int c = tid + i * 512;
      int n = c >> 3, kc = c & 7;
      *reinterpret_cast<int4*>(&Bs[n][kc * 8]) =
          *reinterpret_cast<const int4*>(&w2t[n * 256 + k0 + kc * 8]);
    }
    __syncthreads();
#pragma unroll
    for (int kk = 0; kk < 2; ++kk) {
#pragma unroll
      for (int mi = 0; mi < 2; ++mi) {
        bf16x8 af = *reinterpret_cast<const bf16x8*>(
            &As[waveM * 32 + mi * 16 + l15][k0 + kk * 32 + g * 8]);
#pragma unroll
        for (int ni = 0; ni < 4; ++ni) {
          bf16x8 bfr = *reinterpret_cast<const bf16x8*>(
              &Bs[waveN * 64 + ni * 16 + l15][kk * 32 + g * 8]);
          acc[mi][ni] =
              __builtin_amdgcn_mfma_f32_16x16x32_bf16(af, bfr, acc[mi][ni], 0, 0, 0);
        }
      }
    }
    __syncthreads();
  }
  // epilogue
#pragma unroll
  for (int mi = 0; mi < 2; ++mi) {
#pragma unroll
    for (int ni = 0; ni < 4; ++ni) {
      int col = waveN * 64 + ni * 16 + l15;
#pragma unroll
      for (int r = 0; r < 4; ++r) {
        int row = m0 + waveM * 32 + mi * 16 + g * 4 + r;
        if (row < NN) out[row * 256 + col] = acc[mi][ni][r] + bias2[ni];
      }
    }
  }
}

// ---- launch ---------------------------------------------------------------

extern "C" void kernel_launch(void* const* d_in, const int* in_sizes, int n_in,
                              void* d_out, int out_size, void* d_ws, size_t ws_size,
                              hipStream_t stream) {
  const float* x = (const float*)d_in[0];
  const int* ei = (const int*)d_in[1];
  const float* w1 = (const float*)d_in[2];
  const float* b1 = (const float*)d_in[3];
  const float* w2 = (const float*)d_in[4];
  const float* b2 = (const float*)d_in[5];
  const float* eps = (const float*)d_in[6];
  float* out = (float*)d_out;

  // workspace layout (16B aligned throughout)
  int* cnt = (int*)d_ws;                              // 2 x 10240 ints
  int* bucket = cnt + 20480;                          // NN*BSTRIDE + 32 pad ints
  unsigned short* xb = (unsigned short*)(bucket + NN * BSTRIDE + 32);
  unsigned short* w1t = xb + NN * 256;                // 65536 bf16
  unsigned short* w2t = w1t + 65536;                  // 65536 bf16
  unsigned short* hb = w2t + 65536;                   // NN*256 bf16

  conv_k<<<657, 256, 0, stream>>>(x, w1, w2, (ushort4*)xb, w1t, w2t, cnt);
  fill_k<<<(NE / 4 + 255) / 256, 256, 0, stream>>>(ei, cnt, bucket);
  agg_k<<<NN / 2, 256, 0, stream>>>((const us8*)xb, cnt, bucket, eps, hb);
  mlp_k<<<(NN + 63) / 64, 512, 0, stream>>>(hb, w1t, b1, w2t, b2, out);
}